// Round 5
// baseline (623.246 us; speedup 1.0000x reference)
//
#include <hip/hip_runtime.h>

#define NN 100000
#define NE 3200000
#define DF 512
#define HID 16
#define NC 7
#define NBK 782          // buckets of 128 nodes: ceil(100000/128)
#define BCAP 6144        // per-bucket edge capacity (mean 4096, sigma 64 -> +32 sigma)
#define GEMM_BLOCKS 1563 // 64 rows per block
#define SC_B 256         // scatter blocks

// ---------------- zero int array ----------------
__global__ void k_zero_i(int* __restrict__ p, int n) {
    int i = blockIdx.x * blockDim.x + threadIdx.x;
    if (i < n) p[i] = 0;
}

// ---------------- fused: thin GEMM (h1 = x @ W1) + bucket scatter ----------------
// GEMM blocks: wave = 16 rows, lane = r*4+cc, W1 in LDS, broadcast ds reads.
// Scatter blocks: per-chunk LDS histogram -> one global returning atomic per
// (block,bucket) -> LDS-cursor placement of packed (src | dst_local<<17).
__global__ __launch_bounds__(256) void k_fused(const float* __restrict__ x,
                                               const float* __restrict__ W1,
                                               const int* __restrict__ src,
                                               const int* __restrict__ dst,
                                               float* __restrict__ h1,
                                               int* __restrict__ bcnt,
                                               int* __restrict__ pk) {
    __shared__ float w[DF * HID];  // 32 KB; scatter role aliases it as int[]
    if (blockIdx.x >= GEMM_BLOCKS) {
        int* hist = (int*)w;       // NBK
        int* cur  = hist + NBK;    // NBK
        int b = blockIdx.x - GEMM_BLOCKS;
        const int per = (NE + SC_B - 1) / SC_B;  // 12500
        int e0 = b * per;
        int e1 = min(e0 + per, NE);
        int tid = threadIdx.x;
        for (int i = tid; i < NBK; i += 256) hist[i] = 0;
        __syncthreads();
        for (int e = e0 + tid; e < e1; e += 256) atomicAdd(&hist[dst[e] >> 7], 1);
        __syncthreads();
        for (int i = tid; i < NBK; i += 256) cur[i] = atomicAdd(&bcnt[i], hist[i]);
        __syncthreads();
        for (int e = e0 + tid; e < e1; e += 256) {
            int d = dst[e];
            int bk = d >> 7;
            int pos = atomicAdd(&cur[bk], 1);  // LDS returning atomic (fast)
            if (pos < BCAP) pk[(size_t)bk * BCAP + pos] = src[e] | ((d & 127) << 17);
        }
        return;
    }
    {
        const float4* wg = (const float4*)W1;
        float4* wl = (float4*)w;
#pragma unroll
        for (int i = 0; i < 8; ++i) wl[threadIdx.x + 256 * i] = wg[threadIdx.x + 256 * i];
    }
    __syncthreads();
    int wid = (blockIdx.x * 256 + threadIdx.x) >> 6;
    int lane = threadIdx.x & 63;
    int r = lane >> 2, cc = lane & 3;
    int row = wid * 16 + r;
    if (row >= NN) return;
    const float4* xr = (const float4*)(x + (size_t)row * DF);
    const float4* wl = (const float4*)w;  // float4 index: k*4 + cc
    float4 acc = make_float4(0.f, 0.f, 0.f, 0.f);
#pragma unroll 4
    for (int i = 0; i < DF / 4; ++i) {
        float4 xv = xr[i];
        float4 w0 = wl[(4 * i + 0) * 4 + cc];
        float4 w1v = wl[(4 * i + 1) * 4 + cc];
        float4 w2 = wl[(4 * i + 2) * 4 + cc];
        float4 w3 = wl[(4 * i + 3) * 4 + cc];
        acc.x = fmaf(xv.x, w0.x, fmaf(xv.y, w1v.x, fmaf(xv.z, w2.x, fmaf(xv.w, w3.x, acc.x))));
        acc.y = fmaf(xv.x, w0.y, fmaf(xv.y, w1v.y, fmaf(xv.z, w2.y, fmaf(xv.w, w3.y, acc.y))));
        acc.z = fmaf(xv.x, w0.z, fmaf(xv.y, w1v.z, fmaf(xv.z, w2.z, fmaf(xv.w, w3.z, acc.z))));
        acc.w = fmaf(xv.x, w0.w, fmaf(xv.y, w1v.w, fmaf(xv.z, w2.w, fmaf(xv.w, w3.w, acc.w))));
    }
    *(float4*)(h1 + (size_t)row * HID + cc * 4) = acc;
}

// ---------------- per-bucket degree -> dinv, and scale h1 *= dinv (in place) ----------------
__global__ __launch_bounds__(256) void k_degB(const int* __restrict__ bcnt,
                                              const int* __restrict__ pk,
                                              float* __restrict__ dinv,
                                              float* __restrict__ h1) {
    __shared__ int deg[128];
    __shared__ float dl[128];
    int b = blockIdx.x, tid = threadIdx.x;
    if (tid < 128) deg[tid] = 0;
    __syncthreads();
    int n = min(bcnt[b], BCAP);
    const int* p = pk + (size_t)b * BCAP;
    for (int i = tid; i < n; i += 256) atomicAdd(&deg[p[i] >> 17], 1);
    __syncthreads();
    if (tid < 128) {
        int node = b * 128 + tid;
        float di = rsqrtf((float)deg[tid] + 1.0f);
        dl[tid] = di;
        if (node < NN) dinv[node] = di;
    }
    __syncthreads();
    // scale this bucket's h1 rows by dinv (contiguous 128*16 floats = 512 float4)
    float4* hp = (float4*)(h1 + (size_t)b * 128 * HID);
    for (int i = tid; i < 512; i += 256) {
        int ln = i >> 2;
        int node = b * 128 + ln;
        if (node < NN) {
            float di = dl[ln];
            float4 v = hp[i];
            v.x *= di; v.y *= di; v.z *= di; v.w *= di;
            hp[i] = v;
        }
    }
}

// ---------------- layer-1 bucket aggregate + self + bias + relu + (16->7), h2s = h2*dinv ----------------
__global__ __launch_bounds__(256) void k_agg1(const int* __restrict__ bcnt,
                                              const int* __restrict__ pk,
                                              const float* __restrict__ dinv,
                                              const float* __restrict__ h1s,
                                              const float* __restrict__ b1,
                                              const float* __restrict__ W2,
                                              float* __restrict__ h2s) {
    __shared__ float agg[128 * 17];  // stride-17 pad vs 32 banks
    __shared__ float dl[128];
    int b = blockIdx.x, tid = threadIdx.x;
    for (int i = tid; i < 128 * 17; i += 256) agg[i] = 0.f;
    if (tid < 128) {
        int node = b * 128 + tid;
        dl[tid] = (node < NN) ? dinv[node] : 0.f;
    }
    __syncthreads();
    int n = min(bcnt[b], BCAP);
    const int* p = pk + (size_t)b * BCAP;
    int ch = tid & 15, g = tid >> 4;  // 16 groups of 16 lanes
    for (int i = g; i < n; i += 16) {
        int v = p[i];  // broadcast within group
        int s = v & 0x1FFFF, d = v >> 17;
        float val = h1s[(size_t)s * HID + ch] * dl[d];  // h1s = h1*dinv[s]
        atomicAdd(&agg[d * 17 + ch], val);
    }
    __syncthreads();
    for (int it = 0; it < 8; ++it) {
        int ln = it * 16 + g;
        int node = b * 128 + ln;
        float selfv = (node < NN) ? h1s[(size_t)node * HID + ch] : 0.f;
        float acc = agg[ln * 17 + ch] + selfv * dl[ln] + b1[ch];
        float hr = fmaxf(acc, 0.f);
        float hj = 0.f;
#pragma unroll
        for (int k = 0; k < HID; ++k) {
            float hk = __shfl(hr, k, 16);
            if (ch < NC) hj = fmaf(hk, W2[k * NC + ch], hj);
        }
        if (node < NN && ch < NC) h2s[(size_t)node * NC + ch] = hj * dl[ln];
    }
}

// ---------------- layer-2 bucket aggregate + self + bias + log_softmax ----------------
__global__ __launch_bounds__(256) void k_agg2(const int* __restrict__ bcnt,
                                              const int* __restrict__ pk,
                                              const float* __restrict__ dinv,
                                              const float* __restrict__ h2s,
                                              const float* __restrict__ b2,
                                              float* __restrict__ out) {
    __shared__ float agg[128 * 9];
    __shared__ float dl[128];
    int b = blockIdx.x, tid = threadIdx.x;
    for (int i = tid; i < 128 * 9; i += 256) agg[i] = 0.f;
    if (tid < 128) {
        int node = b * 128 + tid;
        dl[tid] = (node < NN) ? dinv[node] : 0.f;
    }
    __syncthreads();
    int n = min(bcnt[b], BCAP);
    const int* p = pk + (size_t)b * BCAP;
    int ch = tid & 7, g = tid >> 3;  // 32 groups of 8 lanes
    for (int i = g; i < n; i += 32) {
        int v = p[i];
        int s = v & 0x1FFFF, d = v >> 17;
        if (ch < NC) {
            float val = h2s[(size_t)s * NC + ch] * dl[d];  // h2s = h2*dinv[s]
            atomicAdd(&agg[d * 9 + ch], val);
        }
    }
    __syncthreads();
    for (int it = 0; it < 4; ++it) {
        int ln = it * 32 + g;
        int node = b * 128 + ln;
        float selfv = (node < NN && ch < NC) ? h2s[(size_t)node * NC + ch] : 0.f;
        float o = (ch < NC) ? agg[ln * 9 + ch] + selfv * dl[ln] + b2[ch] : -1e30f;
        float m = o;
#pragma unroll
        for (int off = 1; off < 8; off <<= 1) m = fmaxf(m, __shfl_xor(m, off, 8));
        float ex = (ch < NC) ? expf(o - m) : 0.f;
        float s8 = ex;
#pragma unroll
        for (int off = 1; off < 8; off <<= 1) s8 += __shfl_xor(s8, off, 8);
        if (node < NN && ch < NC) out[(size_t)node * NC + ch] = o - m - logf(s8);
    }
}

extern "C" void kernel_launch(void* const* d_in, const int* in_sizes, int n_in,
                              void* d_out, int out_size, void* d_ws, size_t ws_size,
                              hipStream_t stream) {
    const float* x  = (const float*)d_in[0];
    const int*   ei = (const int*)d_in[1];
    const float* W1 = (const float*)d_in[2];
    const float* b1 = (const float*)d_in[3];
    const float* W2 = (const float*)d_in[4];
    const float* b2 = (const float*)d_in[5];
    float* out = (float*)d_out;

    const int* src = ei;       // edge_index[0]
    const int* dst = ei + NE;  // edge_index[1]

    // ws layout (16B-aligned sections):
    // [bcnt 784(int) | pk NBK*BCAP(int) | dinv NN | h1 16NN | h2 7NN]  ~= 28.8 MB
    int*   bcnt = (int*)d_ws;
    int*   pk   = bcnt + 784;
    float* dinv = (float*)(pk + (size_t)NBK * BCAP);
    float* h1   = dinv + NN;
    float* h2   = h1 + (size_t)HID * NN;

    k_zero_i<<<4, 256, 0, stream>>>(bcnt, 784);
    k_fused <<<GEMM_BLOCKS + SC_B, 256, 0, stream>>>(x, W1, src, dst, h1, bcnt, pk);
    k_degB  <<<NBK, 256, 0, stream>>>(bcnt, pk, dinv, h1);
    k_agg1  <<<NBK, 256, 0, stream>>>(bcnt, pk, dinv, h1, b1, W2, h2);
    k_agg2  <<<NBK, 256, 0, stream>>>(bcnt, pk, dinv, h2, b2, out);
}

// Round 6
// 227.304 us; speedup vs baseline: 2.7419x; 2.7419x over previous
//
#include <hip/hip_runtime.h>

#define NN 100000
#define NE 3200000
#define DF 512
#define HID 16
#define NC 7
#define NBK 782          // buckets of 128 nodes
#define BCAP 6144        // per-bucket edge capacity (mean 4096, +32 sigma)
#define GEMM_BLOCKS 1563 // 64 rows per block
#define SC_B 256         // scatter blocks

// ---------------- zero int array ----------------
__global__ void k_zero_i(int* __restrict__ p, int n) {
    int i = blockIdx.x * blockDim.x + threadIdx.x;
    if (i < n) p[i] = 0;
}

// ---------------- fused: thin GEMM (h1 = x @ W1) + bucket scatter ----------------
__global__ __launch_bounds__(256) void k_fused(const float* __restrict__ x,
                                               const float* __restrict__ W1,
                                               const int* __restrict__ src,
                                               const int* __restrict__ dst,
                                               float* __restrict__ h1,
                                               int* __restrict__ bcnt,
                                               int* __restrict__ pk) {
    __shared__ float w[DF * HID];  // 32 KB; scatter role aliases it as int[]
    if (blockIdx.x >= GEMM_BLOCKS) {
        int* hist = (int*)w;       // NBK
        int* cur  = hist + NBK;    // NBK
        int b = blockIdx.x - GEMM_BLOCKS;
        const int per = (NE + SC_B - 1) / SC_B;  // 12500
        int e0 = b * per;
        int e1 = min(e0 + per, NE);
        int tid = threadIdx.x;
        for (int i = tid; i < NBK; i += 256) hist[i] = 0;
        __syncthreads();
        for (int e = e0 + tid; e < e1; e += 256) atomicAdd(&hist[dst[e] >> 7], 1);
        __syncthreads();
        for (int i = tid; i < NBK; i += 256) cur[i] = atomicAdd(&bcnt[i], hist[i]);
        __syncthreads();
        for (int e = e0 + tid; e < e1; e += 256) {
            int d = dst[e];
            int bk = d >> 7;
            int pos = atomicAdd(&cur[bk], 1);  // LDS returning atomic (fast)
            if (pos < BCAP) pk[(size_t)bk * BCAP + pos] = src[e] | ((d & 127) << 17);
        }
        return;
    }
    {
        const float4* wg = (const float4*)W1;
        float4* wl = (float4*)w;
#pragma unroll
        for (int i = 0; i < 8; ++i) wl[threadIdx.x + 256 * i] = wg[threadIdx.x + 256 * i];
    }
    __syncthreads();
    int wid = (blockIdx.x * 256 + threadIdx.x) >> 6;
    int lane = threadIdx.x & 63;
    int r = lane >> 2, cc = lane & 3;
    int row = wid * 16 + r;
    if (row >= NN) return;
    const float4* xr = (const float4*)(x + (size_t)row * DF);
    const float4* wl = (const float4*)w;
    float4 acc = make_float4(0.f, 0.f, 0.f, 0.f);
#pragma unroll 4
    for (int i = 0; i < DF / 4; ++i) {
        float4 xv = xr[i];
        float4 w0 = wl[(4 * i + 0) * 4 + cc];
        float4 w1v = wl[(4 * i + 1) * 4 + cc];
        float4 w2 = wl[(4 * i + 2) * 4 + cc];
        float4 w3 = wl[(4 * i + 3) * 4 + cc];
        acc.x = fmaf(xv.x, w0.x, fmaf(xv.y, w1v.x, fmaf(xv.z, w2.x, fmaf(xv.w, w3.x, acc.x))));
        acc.y = fmaf(xv.x, w0.y, fmaf(xv.y, w1v.y, fmaf(xv.z, w2.y, fmaf(xv.w, w3.y, acc.y))));
        acc.z = fmaf(xv.x, w0.z, fmaf(xv.y, w1v.z, fmaf(xv.z, w2.z, fmaf(xv.w, w3.z, acc.z))));
        acc.w = fmaf(xv.x, w0.w, fmaf(xv.y, w1v.w, fmaf(xv.z, w2.w, fmaf(xv.w, w3.w, acc.w))));
    }
    *(float4*)(h1 + (size_t)row * HID + cc * 4) = acc;
}

// ---------------- per-bucket counting sort (LDS) -> node-contiguous CSR in pk ----------------
// Also: deg -> dinv, per-node ptr/cnt, and h1 *= dinv[row] in place.
__global__ __launch_bounds__(256) void k_sortB(const int* __restrict__ bcnt,
                                               int* __restrict__ pk,
                                               float* __restrict__ dinv,
                                               float* __restrict__ h1,
                                               int* __restrict__ ptrg,
                                               int* __restrict__ cntg) {
    __shared__ int sorted[BCAP];  // 24 KB
    __shared__ int hist[128];
    __shared__ int off[128];
    __shared__ int cur[128];
    __shared__ float dl[128];
    int b = blockIdx.x, tid = threadIdx.x;
    if (tid < 128) hist[tid] = 0;
    __syncthreads();
    int n = min(bcnt[b], BCAP);
    int* p = pk + (size_t)b * BCAP;
    for (int i = tid; i < n; i += 256) atomicAdd(&hist[p[i] >> 17], 1);
    __syncthreads();
    if (tid < 128) off[tid] = hist[tid];
    __syncthreads();
    for (int s2 = 1; s2 < 128; s2 <<= 1) {  // inclusive scan
        int u = 0;
        if (tid < 128 && tid >= s2) u = off[tid - s2];
        __syncthreads();
        if (tid < 128) off[tid] += u;
        __syncthreads();
    }
    if (tid < 128) {
        int start = off[tid] - hist[tid];  // exclusive
        cur[tid] = start;
        int node = b * 128 + tid;
        float di = rsqrtf((float)hist[tid] + 1.0f);
        dl[tid] = di;
        if (node < NN) {
            dinv[node] = di;
            ptrg[node] = b * BCAP + start;
            cntg[node] = hist[tid];
        }
    }
    __syncthreads();
    for (int i = tid; i < n; i += 256) {
        int v = p[i];
        int pos = atomicAdd(&cur[v >> 17], 1);  // LDS returning atomic
        sorted[pos] = v & 0x1FFFF;
    }
    __syncthreads();
    for (int i = tid; i < n; i += 256) p[i] = sorted[i];  // in-place write-back
    // scale this bucket's h1 rows by dinv (128*16 floats = 512 float4)
    float4* hp = (float4*)(h1 + (size_t)b * 128 * HID);
    for (int i = tid; i < 512; i += 256) {
        int ln = i >> 2;
        int node = b * 128 + ln;
        if (node < NN) {
            float di = dl[ln];
            float4 v = hp[i];
            v.x *= di; v.y *= di; v.z *= di; v.w *= di;
            hp[i] = v;
        }
    }
}

// ---------------- layer-1: register aggregate + self + bias + relu + (16->7) ----------------
// 16 lanes per node; h1s pre-scaled by dinv[s]; out = did*(sum + self) + b1.
__global__ __launch_bounds__(256) void k_agg1(const int* __restrict__ ptrg,
                                              const int* __restrict__ cntg,
                                              const int* __restrict__ csr,
                                              const float* __restrict__ dinv,
                                              const float* __restrict__ h1s,
                                              const float* __restrict__ b1,
                                              const float* __restrict__ W2,
                                              float* __restrict__ h2s) {
    int tid = threadIdx.x;
    int ch = tid & 15;
    int d = blockIdx.x * 16 + (tid >> 4);
    if (d >= NN) return;
    int st = ptrg[d], n = cntg[d];
    float did = dinv[d];
    float a0 = 0.f, a1 = 0.f;
    int e = st, end = st + n;
    for (; e + 1 < end; e += 2) {
        int s0 = csr[e], s1 = csr[e + 1];  // broadcast in group
        a0 += h1s[(size_t)s0 * HID + ch];
        a1 += h1s[(size_t)s1 * HID + ch];
    }
    if (e < end) a0 += h1s[(size_t)csr[e] * HID + ch];
    float acc = (a0 + a1 + h1s[(size_t)d * HID + ch]) * did + b1[ch];
    float hr = fmaxf(acc, 0.f);
    float hj = 0.f;
#pragma unroll
    for (int k = 0; k < HID; ++k) {
        float hk = __shfl(hr, k, 16);
        if (ch < NC) hj = fmaf(hk, W2[k * NC + ch], hj);
    }
    if (ch < NC) h2s[(size_t)d * NC + ch] = hj * did;  // pre-scale for layer 2
}

// ---------------- layer-2: register aggregate + self + bias + log_softmax ----------------
__global__ __launch_bounds__(256) void k_agg2(const int* __restrict__ ptrg,
                                              const int* __restrict__ cntg,
                                              const int* __restrict__ csr,
                                              const float* __restrict__ dinv,
                                              const float* __restrict__ h2s,
                                              const float* __restrict__ b2,
                                              float* __restrict__ out) {
    int tid = threadIdx.x;
    int ch = tid & 7;
    int d = blockIdx.x * 32 + (tid >> 3);
    if (d >= NN) return;
    int st = ptrg[d], n = cntg[d];
    float did = dinv[d];
    float a0 = 0.f, a1 = 0.f;
    int e = st, end = st + n;
    for (; e + 1 < end; e += 2) {
        int s0 = csr[e], s1 = csr[e + 1];
        if (ch < NC) {
            a0 += h2s[(size_t)s0 * NC + ch];
            a1 += h2s[(size_t)s1 * NC + ch];
        }
    }
    if (e < end && ch < NC) a0 += h2s[(size_t)csr[e] * NC + ch];
    float o = -1e30f;
    if (ch < NC) o = (a0 + a1 + h2s[(size_t)d * NC + ch]) * did + b2[ch];
    float m = o;
#pragma unroll
    for (int offm = 1; offm < 8; offm <<= 1) m = fmaxf(m, __shfl_xor(m, offm, 8));
    float ex = (ch < NC) ? expf(o - m) : 0.f;
    float s8 = ex;
#pragma unroll
    for (int offm = 1; offm < 8; offm <<= 1) s8 += __shfl_xor(s8, offm, 8);
    if (ch < NC) out[(size_t)d * NC + ch] = o - m - logf(s8);
}

extern "C" void kernel_launch(void* const* d_in, const int* in_sizes, int n_in,
                              void* d_out, int out_size, void* d_ws, size_t ws_size,
                              hipStream_t stream) {
    const float* x  = (const float*)d_in[0];
    const int*   ei = (const int*)d_in[1];
    const float* W1 = (const float*)d_in[2];
    const float* b1 = (const float*)d_in[3];
    const float* W2 = (const float*)d_in[4];
    const float* b2 = (const float*)d_in[5];
    float* out = (float*)d_out;

    const int* src = ei;       // edge_index[0]
    const int* dst = ei + NE;  // edge_index[1]

    // ws layout: [bcnt 784 | pk NBK*BCAP | dinv NN | h1 16NN | h2 7NN | ptrg NN | cntg NN]
    int*   bcnt = (int*)d_ws;
    int*   pk   = bcnt + 784;
    float* dinv = (float*)(pk + (size_t)NBK * BCAP);
    float* h1   = dinv + NN;
    float* h2   = h1 + (size_t)HID * NN;
    int*   ptrg = (int*)(h2 + (size_t)NC * NN);
    int*   cntg = ptrg + NN;

    k_zero_i<<<4, 256, 0, stream>>>(bcnt, 784);
    k_fused <<<GEMM_BLOCKS + SC_B, 256, 0, stream>>>(x, W1, src, dst, h1, bcnt, pk);
    k_sortB <<<NBK, 256, 0, stream>>>(bcnt, pk, dinv, h1, ptrg, cntg);
    k_agg1  <<<(NN + 15) / 16, 256, 0, stream>>>(ptrg, cntg, pk, dinv, h1, b1, W2, h2);
    k_agg2  <<<(NN + 31) / 32, 256, 0, stream>>>(ptrg, cntg, pk, dinv, h2, b2, out);
}

// Round 7
// 197.833 us; speedup vs baseline: 3.1504x; 1.1490x over previous
//
#include <hip/hip_runtime.h>

#define NN 100000
#define NE 3200000
#define DF 512
#define HID 16
#define NC 7
#define NBK 782          // buckets of 128 nodes
#define BCAP 6144        // per-bucket edge capacity (mean 4096, +32 sigma)
#define GEMM_BLOCKS 1563 // 64 rows per block
#define SC_B 640         // scatter blocks
#define SEDG 5000        // edges per scatter block (640*5000 = NE exactly)

// ---------------- zero int array ----------------
__global__ void k_zero_i(int* __restrict__ p, int n) {
    int i = blockIdx.x * blockDim.x + threadIdx.x;
    if (i < n) p[i] = 0;
}

union SMem {
    float w[DF * HID];  // 32 KB, GEMM role
    struct {            // scatter role: 30.4 KB
        int stage[SEDG];
        int off[783];
        int part[256];
        int cur[782];
        int gofs[782];
    } s;
};

// ---------------- fused: bucket scatter (blocks [0,SC_B)) + thin GEMM ----------------
// Scatter: LDS counting-sort by bucket, then coalesced flush of contiguous runs
// into atomically-reserved global ranges. GEMM: W1 in LDS, broadcast ds reads.
__global__ __launch_bounds__(256) void k_fused(const float* __restrict__ x,
                                               const float* __restrict__ W1,
                                               const int* __restrict__ src,
                                               const int* __restrict__ dst,
                                               float* __restrict__ h1,
                                               int* __restrict__ bcnt,
                                               int* __restrict__ pk) {
    __shared__ SMem u;
    int tid = threadIdx.x;
    if (blockIdx.x < SC_B) {
        int* stage = u.s.stage;
        int* off   = u.s.off;
        int* part  = u.s.part;
        int* cur   = u.s.cur;
        int* gofs  = u.s.gofs;
        int e0 = blockIdx.x * SEDG;
        for (int i = tid; i < NBK; i += 256) cur[i] = 0;
        __syncthreads();
        for (int e = e0 + tid; e < e0 + SEDG; e += 256) atomicAdd(&cur[dst[e] >> 7], 1);
        __syncthreads();
        // exclusive scan cur -> off, off[NBK] = SEDG sentinel
        {
            int base = tid * 4;
            int sum = 0;
#pragma unroll
            for (int j = 0; j < 4; ++j) if (base + j < NBK) sum += cur[base + j];
            part[tid] = sum;
            __syncthreads();
            for (int s2 = 1; s2 < 256; s2 <<= 1) {
                int v = (tid >= s2) ? part[tid - s2] : 0;
                __syncthreads();
                part[tid] += v;
                __syncthreads();
            }
            int run = (tid > 0) ? part[tid - 1] : 0;
#pragma unroll
            for (int j = 0; j < 4; ++j) {
                int idx = base + j;
                if (idx < NBK) { off[idx] = run; run += cur[idx]; }
            }
            if (tid == 0) off[NBK] = SEDG;
        }
        __syncthreads();
        // reserve contiguous global ranges; gofs = gbase - local_start; cur := local_start
        for (int i = tid; i < NBK; i += 256) {
            int h = cur[i];
            int g = h ? atomicAdd(&bcnt[i], h) : 0;
            gofs[i] = g - off[i];
            cur[i] = off[i];
        }
        __syncthreads();
        // place into staging, bucket-sorted
        for (int e = e0 + tid; e < e0 + SEDG; e += 256) {
            int d = dst[e];
            int pos = atomicAdd(&cur[d >> 7], 1);  // LDS returning atomic
            stage[pos] = src[e] | ((d & 127) << 17);
        }
        __syncthreads();
        // flush: consecutive i within a bucket run -> consecutive global addresses
        for (int i = tid; i < SEDG; i += 256) {
            int lo = 0, hi = NBK;
            while (hi - lo > 1) { int mid = (lo + hi) >> 1; if (off[mid] <= i) lo = mid; else hi = mid; }
            int idx = gofs[lo] + i;  // position within bucket row
            if (idx < BCAP) pk[(size_t)lo * BCAP + idx] = stage[i];
        }
        return;
    }
    // ---- GEMM role ----
    {
        const float4* wg = (const float4*)W1;
        float4* wl = (float4*)u.w;
#pragma unroll
        for (int i = 0; i < 8; ++i) wl[tid + 256 * i] = wg[tid + 256 * i];
    }
    __syncthreads();
    int wid = (blockIdx.x - SC_B) * 4 + (tid >> 6);
    int lane = tid & 63;
    int r = lane >> 2, cc = lane & 3;
    int row = wid * 16 + r;
    if (row >= NN) return;
    const float4* xr = (const float4*)(x + (size_t)row * DF);
    const float4* wl = (const float4*)u.w;
    float4 acc = make_float4(0.f, 0.f, 0.f, 0.f);
#pragma unroll 4
    for (int i = 0; i < DF / 4; ++i) {
        float4 xv = xr[i];
        float4 w0 = wl[(4 * i + 0) * 4 + cc];
        float4 w1v = wl[(4 * i + 1) * 4 + cc];
        float4 w2 = wl[(4 * i + 2) * 4 + cc];
        float4 w3 = wl[(4 * i + 3) * 4 + cc];
        acc.x = fmaf(xv.x, w0.x, fmaf(xv.y, w1v.x, fmaf(xv.z, w2.x, fmaf(xv.w, w3.x, acc.x))));
        acc.y = fmaf(xv.x, w0.y, fmaf(xv.y, w1v.y, fmaf(xv.z, w2.y, fmaf(xv.w, w3.y, acc.y))));
        acc.z = fmaf(xv.x, w0.z, fmaf(xv.y, w1v.z, fmaf(xv.z, w2.z, fmaf(xv.w, w3.z, acc.z))));
        acc.w = fmaf(xv.x, w0.w, fmaf(xv.y, w1v.w, fmaf(xv.z, w2.w, fmaf(xv.w, w3.w, acc.w))));
    }
    *(float4*)(h1 + (size_t)row * HID + cc * 4) = acc;
}

// ---------------- per-bucket counting sort (LDS) -> node-contiguous CSR in pk ----------------
// Also: deg -> dinv, per-node ptr/cnt, and h1 *= dinv[row] in place.
__global__ __launch_bounds__(256) void k_sortB(const int* __restrict__ bcnt,
                                               int* __restrict__ pk,
                                               float* __restrict__ dinv,
                                               float* __restrict__ h1,
                                               int* __restrict__ ptrg,
                                               int* __restrict__ cntg) {
    __shared__ int sorted[BCAP];  // 24 KB
    __shared__ int hist[128];
    __shared__ int off[128];
    __shared__ int cur[128];
    __shared__ float dl[128];
    int b = blockIdx.x, tid = threadIdx.x;
    if (tid < 128) hist[tid] = 0;
    __syncthreads();
    int n = min(bcnt[b], BCAP);
    int* p = pk + (size_t)b * BCAP;
    for (int i = tid; i < n; i += 256) atomicAdd(&hist[p[i] >> 17], 1);
    __syncthreads();
    if (tid < 128) off[tid] = hist[tid];
    __syncthreads();
    for (int s2 = 1; s2 < 128; s2 <<= 1) {  // inclusive scan
        int u = 0;
        if (tid < 128 && tid >= s2) u = off[tid - s2];
        __syncthreads();
        if (tid < 128) off[tid] += u;
        __syncthreads();
    }
    if (tid < 128) {
        int start = off[tid] - hist[tid];  // exclusive
        cur[tid] = start;
        int node = b * 128 + tid;
        float di = rsqrtf((float)hist[tid] + 1.0f);
        dl[tid] = di;
        if (node < NN) {
            dinv[node] = di;
            ptrg[node] = b * BCAP + start;
            cntg[node] = hist[tid];
        }
    }
    __syncthreads();
    for (int i = tid; i < n; i += 256) {
        int v = p[i];
        int pos = atomicAdd(&cur[v >> 17], 1);  // LDS returning atomic
        sorted[pos] = v & 0x1FFFF;
    }
    __syncthreads();
    for (int i = tid; i < n; i += 256) p[i] = sorted[i];  // in-place write-back
    // scale this bucket's h1 rows by dinv (128*16 floats = 512 float4)
    float4* hp = (float4*)(h1 + (size_t)b * 128 * HID);
    for (int i = tid; i < 512; i += 256) {
        int ln = i >> 2;
        int node = b * 128 + ln;
        if (node < NN) {
            float di = dl[ln];
            float4 v = hp[i];
            v.x *= di; v.y *= di; v.z *= di; v.w *= di;
            hp[i] = v;
        }
    }
}

// ---------------- layer-1: register aggregate + self + bias + relu + (16->7) ----------------
__global__ __launch_bounds__(256) void k_agg1(const int* __restrict__ ptrg,
                                              const int* __restrict__ cntg,
                                              const int* __restrict__ csr,
                                              const float* __restrict__ dinv,
                                              const float* __restrict__ h1s,
                                              const float* __restrict__ b1,
                                              const float* __restrict__ W2,
                                              float* __restrict__ h2s) {
    int tid = threadIdx.x;
    int ch = tid & 15;
    int d = blockIdx.x * 16 + (tid >> 4);
    if (d >= NN) return;
    int st = ptrg[d], n = cntg[d];
    float did = dinv[d];
    float a0 = 0.f, a1 = 0.f;
    int e = st, end = st + n;
    for (; e + 1 < end; e += 2) {
        int s0 = csr[e], s1 = csr[e + 1];  // broadcast in group
        a0 += h1s[(size_t)s0 * HID + ch];
        a1 += h1s[(size_t)s1 * HID + ch];
    }
    if (e < end) a0 += h1s[(size_t)csr[e] * HID + ch];
    float acc = (a0 + a1 + h1s[(size_t)d * HID + ch]) * did + b1[ch];
    float hr = fmaxf(acc, 0.f);
    float hj = 0.f;
#pragma unroll
    for (int k = 0; k < HID; ++k) {
        float hk = __shfl(hr, k, 16);
        if (ch < NC) hj = fmaf(hk, W2[k * NC + ch], hj);
    }
    if (ch < NC) h2s[(size_t)d * NC + ch] = hj * did;  // pre-scale for layer 2
}

// ---------------- layer-2: register aggregate + self + bias + log_softmax ----------------
__global__ __launch_bounds__(256) void k_agg2(const int* __restrict__ ptrg,
                                              const int* __restrict__ cntg,
                                              const int* __restrict__ csr,
                                              const float* __restrict__ dinv,
                                              const float* __restrict__ h2s,
                                              const float* __restrict__ b2,
                                              float* __restrict__ out) {
    int tid = threadIdx.x;
    int ch = tid & 7;
    int d = blockIdx.x * 32 + (tid >> 3);
    if (d >= NN) return;
    int st = ptrg[d], n = cntg[d];
    float did = dinv[d];
    float a0 = 0.f, a1 = 0.f;
    int e = st, end = st + n;
    for (; e + 1 < end; e += 2) {
        int s0 = csr[e], s1 = csr[e + 1];
        if (ch < NC) {
            a0 += h2s[(size_t)s0 * NC + ch];
            a1 += h2s[(size_t)s1 * NC + ch];
        }
    }
    if (e < end && ch < NC) a0 += h2s[(size_t)csr[e] * NC + ch];
    float o = -1e30f;
    if (ch < NC) o = (a0 + a1 + h2s[(size_t)d * NC + ch]) * did + b2[ch];
    float m = o;
#pragma unroll
    for (int offm = 1; offm < 8; offm <<= 1) m = fmaxf(m, __shfl_xor(m, offm, 8));
    float ex = (ch < NC) ? expf(o - m) : 0.f;
    float s8 = ex;
#pragma unroll
    for (int offm = 1; offm < 8; offm <<= 1) s8 += __shfl_xor(s8, offm, 8);
    if (ch < NC) out[(size_t)d * NC + ch] = o - m - logf(s8);
}

extern "C" void kernel_launch(void* const* d_in, const int* in_sizes, int n_in,
                              void* d_out, int out_size, void* d_ws, size_t ws_size,
                              hipStream_t stream) {
    const float* x  = (const float*)d_in[0];
    const int*   ei = (const int*)d_in[1];
    const float* W1 = (const float*)d_in[2];
    const float* b1 = (const float*)d_in[3];
    const float* W2 = (const float*)d_in[4];
    const float* b2 = (const float*)d_in[5];
    float* out = (float*)d_out;

    const int* src = ei;       // edge_index[0]
    const int* dst = ei + NE;  // edge_index[1]

    // ws layout: [bcnt 784 | pk NBK*BCAP | dinv NN | h1 16NN | h2 7NN | ptrg NN | cntg NN]
    int*   bcnt = (int*)d_ws;
    int*   pk   = bcnt + 784;
    float* dinv = (float*)(pk + (size_t)NBK * BCAP);
    float* h1   = dinv + NN;
    float* h2   = h1 + (size_t)HID * NN;
    int*   ptrg = (int*)(h2 + (size_t)NC * NN);
    int*   cntg = ptrg + NN;

    k_zero_i<<<4, 256, 0, stream>>>(bcnt, 784);
    k_fused <<<SC_B + GEMM_BLOCKS, 256, 0, stream>>>(x, W1, src, dst, h1, bcnt, pk);
    k_sortB <<<NBK, 256, 0, stream>>>(bcnt, pk, dinv, h1, ptrg, cntg);
    k_agg1  <<<(NN + 15) / 16, 256, 0, stream>>>(ptrg, cntg, pk, dinv, h1, b1, W2, h2);
    k_agg2  <<<(NN + 31) / 32, 256, 0, stream>>>(ptrg, cntg, pk, dinv, h2, b2, out);
}

// Round 8
// 193.107 us; speedup vs baseline: 3.2275x; 1.0245x over previous
//
#include <hip/hip_runtime.h>

#define NN 100000
#define NE 3200000
#define DF 512
#define HID 16
#define NC 7
#define NBK 782          // buckets of 128 nodes
#define BCAP 6144        // per-bucket edge capacity (mean 4096, +32 sigma)
#define GEMM_BLOCKS 782  // 128 rows per block (8 waves x 16 rows)
#define SC_B 640         // scatter blocks
#define SEDG 5000        // edges per scatter block (640*5000 = NE exactly)

// ---------------- zero int array ----------------
__global__ void k_zero_i(int* __restrict__ p, int n) {
    int i = blockIdx.x * blockDim.x + threadIdx.x;
    if (i < n) p[i] = 0;
}

union SMem {
    float w[DF * HID];  // 32 KB, GEMM role
    struct {            // scatter role: 31.4 KB
        int stage[SEDG];
        int off[783];
        int part[512];
        int cur[782];
        int gofs[782];
    } s;
};

// ---------------- fused: bucket scatter (blocks [0,SC_B)) + thin GEMM ----------------
__global__ __launch_bounds__(512) void k_fused(const float* __restrict__ x,
                                               const float* __restrict__ W1,
                                               const int* __restrict__ src,
                                               const int* __restrict__ dst,
                                               float* __restrict__ h1,
                                               int* __restrict__ bcnt,
                                               int* __restrict__ pk) {
    __shared__ SMem u;
    int tid = threadIdx.x;
    if (blockIdx.x < SC_B) {
        int* stage = u.s.stage;
        int* off   = u.s.off;
        int* part  = u.s.part;
        int* cur   = u.s.cur;
        int* gofs  = u.s.gofs;
        int e0 = blockIdx.x * SEDG;
        for (int i = tid; i < NBK; i += 512) cur[i] = 0;
        __syncthreads();
        for (int e = e0 + tid; e < e0 + SEDG; e += 512) atomicAdd(&cur[dst[e] >> 7], 1);
        __syncthreads();
        // exclusive scan cur -> off (512-thread, 2 buckets/thread), off[NBK]=SEDG
        {
            int base = tid * 2;
            int sum = 0;
#pragma unroll
            for (int j = 0; j < 2; ++j) if (base + j < NBK) sum += cur[base + j];
            part[tid] = sum;
            __syncthreads();
            for (int s2 = 1; s2 < 512; s2 <<= 1) {
                int v = (tid >= s2) ? part[tid - s2] : 0;
                __syncthreads();
                part[tid] += v;
                __syncthreads();
            }
            int run = (tid > 0) ? part[tid - 1] : 0;
#pragma unroll
            for (int j = 0; j < 2; ++j) {
                int idx = base + j;
                if (idx < NBK) { off[idx] = run; run += cur[idx]; }
            }
            if (tid == 0) off[NBK] = SEDG;
        }
        __syncthreads();
        // reserve contiguous global ranges; gofs = gbase - local_start; cur := local_start
        for (int i = tid; i < NBK; i += 512) {
            int h = cur[i];
            int g = h ? atomicAdd(&bcnt[i], h) : 0;
            gofs[i] = g - off[i];
            cur[i] = off[i];
        }
        __syncthreads();
        // place into staging, bucket-sorted
        for (int e = e0 + tid; e < e0 + SEDG; e += 512) {
            int d = dst[e];
            int pos = atomicAdd(&cur[d >> 7], 1);  // LDS returning atomic
            stage[pos] = src[e] | ((d & 127) << 17);
        }
        __syncthreads();
        // flush: consecutive i within a bucket run -> consecutive global addresses
        for (int i = tid; i < SEDG; i += 512) {
            int lo = 0, hi = NBK;
            while (hi - lo > 1) { int mid = (lo + hi) >> 1; if (off[mid] <= i) lo = mid; else hi = mid; }
            int idx = gofs[lo] + i;  // position within bucket row
            if (idx < BCAP) pk[(size_t)lo * BCAP + idx] = stage[i];
        }
        return;
    }
    // ---- GEMM role: 8 waves x 16 rows = 128 rows/block ----
    {
        const float4* wg = (const float4*)W1;
        float4* wl = (float4*)u.w;
#pragma unroll
        for (int i = 0; i < 4; ++i) wl[tid + 512 * i] = wg[tid + 512 * i];
    }
    __syncthreads();
    int wid = (blockIdx.x - SC_B) * 8 + (tid >> 6);
    int lane = tid & 63;
    int r = lane >> 2, cc = lane & 3;
    int row = wid * 16 + r;
    if (row >= NN) return;
    const float4* xr = (const float4*)(x + (size_t)row * DF);
    const float4* wl = (const float4*)u.w;
    float4 acc = make_float4(0.f, 0.f, 0.f, 0.f);
#pragma unroll 8
    for (int i = 0; i < DF / 4; ++i) {
        float4 xv = xr[i];
        float4 w0 = wl[(4 * i + 0) * 4 + cc];
        float4 w1v = wl[(4 * i + 1) * 4 + cc];
        float4 w2 = wl[(4 * i + 2) * 4 + cc];
        float4 w3 = wl[(4 * i + 3) * 4 + cc];
        acc.x = fmaf(xv.x, w0.x, fmaf(xv.y, w1v.x, fmaf(xv.z, w2.x, fmaf(xv.w, w3.x, acc.x))));
        acc.y = fmaf(xv.x, w0.y, fmaf(xv.y, w1v.y, fmaf(xv.z, w2.y, fmaf(xv.w, w3.y, acc.y))));
        acc.z = fmaf(xv.x, w0.z, fmaf(xv.y, w1v.z, fmaf(xv.z, w2.z, fmaf(xv.w, w3.z, acc.z))));
        acc.w = fmaf(xv.x, w0.w, fmaf(xv.y, w1v.w, fmaf(xv.z, w2.w, fmaf(xv.w, w3.w, acc.w))));
    }
    *(float4*)(h1 + (size_t)row * HID + cc * 4) = acc;
}

// ---------------- per-bucket counting sort (LDS) -> node-contiguous CSR in pk ----------------
__global__ __launch_bounds__(256) void k_sortB(const int* __restrict__ bcnt,
                                               int* __restrict__ pk,
                                               float* __restrict__ dinv,
                                               float* __restrict__ h1,
                                               int* __restrict__ ptrg,
                                               int* __restrict__ cntg) {
    __shared__ int sorted[BCAP];  // 24 KB
    __shared__ int hist[128];
    __shared__ int off[128];
    __shared__ int cur[128];
    __shared__ float dl[128];
    int b = blockIdx.x, tid = threadIdx.x;
    if (tid < 128) hist[tid] = 0;
    __syncthreads();
    int n = min(bcnt[b], BCAP);
    int* p = pk + (size_t)b * BCAP;
    for (int i = tid; i < n; i += 256) atomicAdd(&hist[p[i] >> 17], 1);
    __syncthreads();
    if (tid < 128) off[tid] = hist[tid];
    __syncthreads();
    for (int s2 = 1; s2 < 128; s2 <<= 1) {  // inclusive scan
        int u = 0;
        if (tid < 128 && tid >= s2) u = off[tid - s2];
        __syncthreads();
        if (tid < 128) off[tid] += u;
        __syncthreads();
    }
    if (tid < 128) {
        int start = off[tid] - hist[tid];  // exclusive
        cur[tid] = start;
        int node = b * 128 + tid;
        float di = rsqrtf((float)hist[tid] + 1.0f);
        dl[tid] = di;
        if (node < NN) {
            dinv[node] = di;
            ptrg[node] = b * BCAP + start;
            cntg[node] = hist[tid];
        }
    }
    __syncthreads();
    for (int i = tid; i < n; i += 256) {
        int v = p[i];
        int pos = atomicAdd(&cur[v >> 17], 1);  // LDS returning atomic
        sorted[pos] = v & 0x1FFFF;
    }
    __syncthreads();
    for (int i = tid; i < n; i += 256) p[i] = sorted[i];  // in-place write-back
    float4* hp = (float4*)(h1 + (size_t)b * 128 * HID);
    for (int i = tid; i < 512; i += 256) {
        int ln = i >> 2;
        int node = b * 128 + ln;
        if (node < NN) {
            float di = dl[ln];
            float4 v = hp[i];
            v.x *= di; v.y *= di; v.z *= di; v.w *= di;
            hp[i] = v;
        }
    }
}

// ---------------- layer-1: register aggregate + self + bias + relu + (16->7) ----------------
__global__ __launch_bounds__(256) void k_agg1(const int* __restrict__ ptrg,
                                              const int* __restrict__ cntg,
                                              const int* __restrict__ csr,
                                              const float* __restrict__ dinv,
                                              const float* __restrict__ h1s,
                                              const float* __restrict__ b1,
                                              const float* __restrict__ W2,
                                              float* __restrict__ h2s) {
    int tid = threadIdx.x;
    int ch = tid & 15;
    int d = blockIdx.x * 16 + (tid >> 4);
    if (d >= NN) return;
    int st = ptrg[d], n = cntg[d];
    float did = dinv[d];
    float a0 = 0.f, a1 = 0.f;
    int e = st, end = st + n;
    for (; e + 1 < end; e += 2) {
        int s0 = csr[e], s1 = csr[e + 1];  // broadcast in group
        a0 += h1s[(size_t)s0 * HID + ch];
        a1 += h1s[(size_t)s1 * HID + ch];
    }
    if (e < end) a0 += h1s[(size_t)csr[e] * HID + ch];
    float acc = (a0 + a1 + h1s[(size_t)d * HID + ch]) * did + b1[ch];
    float hr = fmaxf(acc, 0.f);
    float hj = 0.f;
#pragma unroll
    for (int k = 0; k < HID; ++k) {
        float hk = __shfl(hr, k, 16);
        if (ch < NC) hj = fmaf(hk, W2[k * NC + ch], hj);
    }
    if (ch < NC) h2s[(size_t)d * NC + ch] = hj * did;  // pre-scale for layer 2
}

// ---------------- layer-2: register aggregate + self + bias + log_softmax ----------------
__global__ __launch_bounds__(256) void k_agg2(const int* __restrict__ ptrg,
                                              const int* __restrict__ cntg,
                                              const int* __restrict__ csr,
                                              const float* __restrict__ dinv,
                                              const float* __restrict__ h2s,
                                              const float* __restrict__ b2,
                                              float* __restrict__ out) {
    int tid = threadIdx.x;
    int ch = tid & 7;
    int d = blockIdx.x * 32 + (tid >> 3);
    if (d >= NN) return;
    int st = ptrg[d], n = cntg[d];
    float did = dinv[d];
    float a0 = 0.f, a1 = 0.f;
    int e = st, end = st + n;
    for (; e + 1 < end; e += 2) {
        int s0 = csr[e], s1 = csr[e + 1];
        if (ch < NC) {
            a0 += h2s[(size_t)s0 * NC + ch];
            a1 += h2s[(size_t)s1 * NC + ch];
        }
    }
    if (e < end && ch < NC) a0 += h2s[(size_t)csr[e] * NC + ch];
    float o = -1e30f;
    if (ch < NC) o = (a0 + a1 + h2s[(size_t)d * NC + ch]) * did + b2[ch];
    float m = o;
#pragma unroll
    for (int offm = 1; offm < 8; offm <<= 1) m = fmaxf(m, __shfl_xor(m, offm, 8));
    float ex = (ch < NC) ? expf(o - m) : 0.f;
    float s8 = ex;
#pragma unroll
    for (int offm = 1; offm < 8; offm <<= 1) s8 += __shfl_xor(s8, offm, 8);
    if (ch < NC) out[(size_t)d * NC + ch] = o - m - logf(s8);
}

extern "C" void kernel_launch(void* const* d_in, const int* in_sizes, int n_in,
                              void* d_out, int out_size, void* d_ws, size_t ws_size,
                              hipStream_t stream) {
    const float* x  = (const float*)d_in[0];
    const int*   ei = (const int*)d_in[1];
    const float* W1 = (const float*)d_in[2];
    const float* b1 = (const float*)d_in[3];
    const float* W2 = (const float*)d_in[4];
    const float* b2 = (const float*)d_in[5];
    float* out = (float*)d_out;

    const int* src = ei;       // edge_index[0]
    const int* dst = ei + NE;  // edge_index[1]

    // ws layout: [bcnt 784 | pk NBK*BCAP | dinv NN | h1 16NN | h2 7NN | ptrg NN | cntg NN]
    int*   bcnt = (int*)d_ws;
    int*   pk   = bcnt + 784;
    float* dinv = (float*)(pk + (size_t)NBK * BCAP);
    float* h1   = dinv + NN;
    float* h2   = h1 + (size_t)HID * NN;
    int*   ptrg = (int*)(h2 + (size_t)NC * NN);
    int*   cntg = ptrg + NN;

    k_zero_i<<<4, 256, 0, stream>>>(bcnt, 784);
    k_fused <<<SC_B + GEMM_BLOCKS, 512, 0, stream>>>(x, W1, src, dst, h1, bcnt, pk);
    k_sortB <<<NBK, 256, 0, stream>>>(bcnt, pk, dinv, h1, ptrg, cntg);
    k_agg1  <<<(NN + 15) / 16, 256, 0, stream>>>(ptrg, cntg, pk, dinv, h1, b1, W2, h2);
    k_agg2  <<<(NN + 31) / 32, 256, 0, stream>>>(ptrg, cntg, pk, dinv, h2, b2, out);
}